// Round 1
// 507.788 us; speedup vs baseline: 1.1664x; 1.1664x over previous
//
#include <hip/hip_runtime.h>
#include <stdint.h>

// Problem constants
#define BATCH   32768
#define F_IN    64
#define HID     32
#define E_LEN   25
#define N_HG    96           // H*G
#define BN_EPS  1e-5f

#define NBLK1   512          // k1 blocks (64 threads each, 1 row/thread)

// ws layout (bytes)
#define WS_WT   0            // 96*25*32 f16 = 153600 B (u32-paired)
#define WS_P1   153600       // 512*32 f32 partial sums      (65536)
#define WS_P2   219136       // 512*32 f32 partial sumsq     (65536)
#define WS_SS   284672       // 64 f32: scale[32], shift[32]
#define WS_H2   284928       // 32768*32 f32 h2 rows (4 MB)

typedef _Float16 half2_t __attribute__((ext_vector_type(2)));

__device__ __forceinline__ float selu_f(float x) {
    const float lam = 1.0507009873554805f;
    const float la  = 1.7580993408473766f;   // lam * alpha
    return x > 0.f ? lam * x : la * (__expf(x) - 1.f);
}

__device__ __forceinline__ float dot2f(uint32_t w, uint32_t e, float acc) {
    return __builtin_amdgcn_fdot2(__builtin_bit_cast(half2_t, w),
                                  __builtin_bit_cast(half2_t, e), acc, false);
}

// Shared feature extractor up to h2 (pre-BN). One row per thread.
__device__ __forceinline__ void compute_h2(const float* __restrict__ xr,
                                           const float* __restrict__ W1,
                                           const float* __restrict__ b1,
                                           const float* __restrict__ W2,
                                           const float* __restrict__ b2,
                                           float h2[HID]) {
    float x[F_IN];
    const float4* x4 = (const float4*)xr;
#pragma unroll
    for (int i = 0; i < F_IN / 4; ++i) {
        float4 v = x4[i];
        x[4*i] = v.x; x[4*i+1] = v.y; x[4*i+2] = v.z; x[4*i+3] = v.w;
    }
    float h[HID];
#pragma unroll
    for (int j = 0; j < HID; ++j) h[j] = b1[j];
#pragma unroll 4
    for (int i = 0; i < F_IN; ++i) {
        float xi = x[i];
#pragma unroll
        for (int j = 0; j < HID; ++j) h[j] = fmaf(xi, W1[i*HID + j], h[j]);
    }
#pragma unroll
    for (int j = 0; j < HID; ++j) h[j] = selu_f(h[j]);
#pragma unroll
    for (int j = 0; j < HID; ++j) h2[j] = b2[j];
#pragma unroll 4
    for (int k = 0; k < HID; ++k) {
        float hk = h[k];
#pragma unroll
        for (int j = 0; j < HID; ++j) h2[j] = fmaf(hk, W2[k*HID + j], h2[j]);
    }
}

// K0: Wh [96][32][25] f32  ->  wt16 [96][25][32] f16  (dot2-pair friendly)
__global__ __launch_bounds__(256) void k0_weights(const float* __restrict__ Wh,
                                                  uint16_t* __restrict__ wt16) {
    int t = blockIdx.x * 256 + threadIdx.x;
    if (t >= N_HG * E_LEN * HID) return;
    int hg = t / (E_LEN * HID);
    int r  = t % (E_LEN * HID);
    int ee = r / HID;
    int f  = r % HID;
    float v = Wh[hg * (HID * E_LEN) + f * E_LEN + ee];
    _Float16 hv = (_Float16)v;
    wt16[t] = __builtin_bit_cast(uint16_t, hv);
}

// K1: compute h2, store it, emit per-block (sum, sumsq) partials. 64 thr/blk.
__global__ __launch_bounds__(64) void k1_stats(const float* __restrict__ inp,
                                               const float* __restrict__ W1,
                                               const float* __restrict__ b1,
                                               const float* __restrict__ W2,
                                               const float* __restrict__ b2,
                                               float* __restrict__ h2out,
                                               float* __restrict__ p1,
                                               float* __restrict__ p2) {
    int row  = blockIdx.x * 64 + threadIdx.x;
    int lane = threadIdx.x;

    float h2[HID];
    compute_h2(inp + (size_t)row * F_IN, W1, b1, W2, b2, h2);

    float4* dst = (float4*)(h2out + (size_t)row * HID);
#pragma unroll
    for (int k = 0; k < HID / 4; ++k)
        dst[k] = make_float4(h2[4*k], h2[4*k+1], h2[4*k+2], h2[4*k+3]);

#pragma unroll
    for (int j = 0; j < HID; ++j) {
        float a = h2[j];
        float b = h2[j] * h2[j];
#pragma unroll
        for (int off = 32; off > 0; off >>= 1) {
            a += __shfl_xor(a, off, 64);
            b += __shfl_xor(b, off, 64);
        }
        if (lane == 0) { p1[blockIdx.x * HID + j] = a; p2[blockIdx.x * HID + j] = b; }
    }
}

// K2: fold NBLK1 partials -> scale/shift per feature.
__global__ __launch_bounds__(256) void k2_fold(const float* __restrict__ p1,
                                               const float* __restrict__ p2,
                                               const float* __restrict__ gamma,
                                               const float* __restrict__ beta,
                                               float* __restrict__ ss) {
    __shared__ float l1[8][HID];
    __shared__ float l2[8][HID];
    int f = threadIdx.x & 31;
    int c = threadIdx.x >> 5;
    float a = 0.f, b = 0.f;
    for (int i = c; i < NBLK1; i += 8) {
        a += p1[i * HID + f];
        b += p2[i * HID + f];
    }
    l1[c][f] = a; l2[c][f] = b;
    __syncthreads();
    if (threadIdx.x < HID) {
        float A = 0.f, Bv = 0.f;
#pragma unroll
        for (int i = 0; i < 8; ++i) { A += l1[i][f]; Bv += l2[i][f]; }
        float mu  = A * (1.0f / (float)BATCH);
        float var = Bv * (1.0f / (float)BATCH) - mu * mu;
        float sc  = gamma[f] * rsqrtf(var + BN_EPS);
        ss[f]        = sc;
        ss[HID + f]  = beta[f] - mu * sc;
    }
}

// K4 v2: BN+SELU (e), heads GEMM + SELU + L1 normalize, LDS-transposed
// coalesced stores.
//
// Changes vs v1 (theory: latency-bound on non-scalar weight loads +
// per-chunk vmcnt(0) barrier drains):
//  - 512 threads = 8 waves over the SAME 64 rows; each wave owns exactly
//    one group per chunk -> occupancy 8 -> 16 waves/CU, half the serial
//    work per wave.
//  - wave id forced into an SGPR via readfirstlane so the weight/bias
//    pointers are COMPILER-uniform -> s_load_dwordx16 weight batches
//    (group weight rows are 64B-aligned), dot2 consumes the SGPR operand.
//  - raw s_barrier + lgkmcnt(0) instead of __syncthreads(): the barriers
//    only order LDS traffic; global stores are never drained inside the
//    loop (no vmcnt(0) round-trips), they retire continuously at HBM rate.
#define TROWS 64
#define TSTR  201            // LDS row stride in f32 (odd -> conflict-free stage)

__global__ __launch_bounds__(512, 4) void k4_heads(const float* __restrict__ h2buf,
                                                   const float* __restrict__ ss,
                                                   const uint32_t* __restrict__ wt,
                                                   const float* __restrict__ bh,
                                                   float* __restrict__ out) {
    __shared__ float tile[TROWS * TSTR];    // 51456 B

    int lane = threadIdx.x & 63;
    int wave = __builtin_amdgcn_readfirstlane((int)(threadIdx.x >> 6)); // 0..7, SGPR
    int r0   = blockIdx.x * TROWS;
    int row  = r0 + lane;

    // Build packed f16 e-row in registers: e = selu(h2*scale + shift)
    uint32_t e2[HID / 2];
    {
        const float4* hp = (const float4*)(h2buf + (size_t)row * HID);
#pragma unroll
        for (int k = 0; k < HID / 4; ++k) {
            float4 v = hp[k];
            float e0 = selu_f(fmaf(v.x, ss[4*k+0], ss[HID + 4*k+0]));
            float e1 = selu_f(fmaf(v.y, ss[4*k+1], ss[HID + 4*k+1]));
            float e2v = selu_f(fmaf(v.z, ss[4*k+2], ss[HID + 4*k+2]));
            float e3 = selu_f(fmaf(v.w, ss[4*k+3], ss[HID + 4*k+3]));
            half2_t p0; p0[0] = (_Float16)e0; p0[1] = (_Float16)e1;
            half2_t p1; p1[0] = (_Float16)e2v; p1[1] = (_Float16)e3;
            e2[2*k]   = __builtin_bit_cast(uint32_t, p0);
            e2[2*k+1] = __builtin_bit_cast(uint32_t, p1);
        }
    }

    for (int c = 0; c < 12; ++c) {          // 12 chunks x 8 groups (1/wave)
        int hg = c * 8 + wave;              // uniform (SGPR)
        const uint32_t* w   = wt + hg * (E_LEN * HID / 2);  // uniform -> s_load
        const float*    bia = bh + hg * E_LEN;              // uniform -> s_load

        float d[E_LEN];
        float l1 = 0.f;
#pragma unroll
        for (int ee = 0; ee < E_LEN; ++ee) {
            float acc = bia[ee];
#pragma unroll
            for (int k = 0; k < HID / 2; ++k)
                acc = dot2f(w[ee * (HID / 2) + k], e2[k], acc);
            float dv = selu_f(acc);
            d[ee] = dv;
            l1 += fabsf(dv);
        }
        float inv = 1.0f / fmaxf(l1, 1e-12f);
        float* t = &tile[lane * TSTR + wave * E_LEN];
#pragma unroll
        for (int ee = 0; ee < E_LEN; ++ee)
            t[ee] = d[ee] * inv;

        // LDS-only barrier: stage writes visible to all waves; global
        // stores from the previous flush are NOT drained here.
        asm volatile("s_waitcnt lgkmcnt(0)" ::: "memory");
        __builtin_amdgcn_s_barrier();

        // flush: 64 rows x 200 f32 = 3200 float4, lane-consecutive
        float* ob = out + (size_t)r0 * (N_HG * E_LEN) + c * 200;
        for (int f4 = threadIdx.x; f4 < 3200; f4 += 512) {
            int rr = f4 / 50;               // 50 float4 per row-chunk
            int w4 = f4 % 50;
            const float* src = &tile[rr * TSTR + w4 * 4];
            float4 v;
            v.x = src[0]; v.y = src[1]; v.z = src[2]; v.w = src[3];
            *(float4*)(ob + (size_t)rr * (N_HG * E_LEN) + w4 * 4) = v;
        }

        // LDS-only barrier: all flush reads done before tile is re-staged.
        asm volatile("s_waitcnt lgkmcnt(0)" ::: "memory");
        __builtin_amdgcn_s_barrier();
    }
}

extern "C" void kernel_launch(void* const* d_in, const int* in_sizes, int n_in,
                              void* d_out, int out_size, void* d_ws, size_t ws_size,
                              hipStream_t stream) {
    const float* inp   = (const float*)d_in[0];
    const float* W1    = (const float*)d_in[1];
    const float* b1    = (const float*)d_in[2];
    const float* W2    = (const float*)d_in[3];
    const float* b2    = (const float*)d_in[4];
    const float* gamma = (const float*)d_in[5];
    const float* beta  = (const float*)d_in[6];
    const float* Wh    = (const float*)d_in[7];
    const float* bh    = (const float*)d_in[8];
    float* out = (float*)d_out;

    char* ws = (char*)d_ws;
    uint16_t* wt16 = (uint16_t*)(ws + WS_WT);
    uint32_t* wtq  = (uint32_t*)(ws + WS_WT);
    float*    p1   = (float*)(ws + WS_P1);
    float*    p2   = (float*)(ws + WS_P2);
    float*    ssb  = (float*)(ws + WS_SS);
    float*    h2b  = (float*)(ws + WS_H2);

    hipLaunchKernelGGL(k0_weights, dim3(300),   dim3(256), 0, stream, Wh, wt16);
    hipLaunchKernelGGL(k1_stats,   dim3(NBLK1), dim3(64),  0, stream, inp, W1, b1, W2, b2, h2b, p1, p2);
    hipLaunchKernelGGL(k2_fold,    dim3(1),     dim3(256), 0, stream, p1, p2, gamma, beta, ssb);
    hipLaunchKernelGGL(k4_heads,   dim3(BATCH / TROWS), dim3(512), 0, stream, h2b, ssb, wtq, bh, out);
}

// Round 3
// 421.552 us; speedup vs baseline: 1.4050x; 1.2046x over previous
//
#include <hip/hip_runtime.h>
#include <stdint.h>

// Problem constants
#define BATCH   32768
#define F_IN    64
#define HID     32
#define E_LEN   25
#define N_HG    96           // H*G
#define BN_EPS  1e-5f

#define NBLK1   256          // k1 blocks (128 threads, 1 row/thread)

// ws layout (bytes) -- total 4473088
#define WS_WA   0            // MFMA A-fragments: 96 hg * 2 tiles * 64 lanes * 16 B = 196608
#define WS_BH   196608       // padded bias 96*32 f32 = 12288 (region 16384)
#define WS_P1   212992       // 256*32 f32 partial sums   (32768)
#define WS_P2   245760       // 256*32 f32 partial sumsq  (32768)
#define WS_SS   278528       // 64 f32: scale[32], shift[32] (256)
#define WS_H2   278784       // 32768*32 f32 h2 rows (4 MB)

typedef _Float16 half2_t __attribute__((ext_vector_type(2)));
typedef _Float16 f16x8   __attribute__((ext_vector_type(8)));
typedef float    f32x4   __attribute__((ext_vector_type(4)));

__device__ __forceinline__ float selu_f(float x) {
    const float lam = 1.0507009873554805f;
    const float la  = 1.7580993408473766f;   // lam * alpha
    return x > 0.f ? lam * x : la * (__expf(x) - 1.f);
}

// Shared feature extractor up to h2 (pre-BN). One row per thread.
__device__ __forceinline__ void compute_h2(const float* __restrict__ xr,
                                           const float* __restrict__ W1,
                                           const float* __restrict__ b1,
                                           const float* __restrict__ W2,
                                           const float* __restrict__ b2,
                                           float h2[HID]) {
    float x[F_IN];
    const float4* x4 = (const float4*)xr;
#pragma unroll
    for (int i = 0; i < F_IN / 4; ++i) {
        float4 v = x4[i];
        x[4*i] = v.x; x[4*i+1] = v.y; x[4*i+2] = v.z; x[4*i+3] = v.w;
    }
    float h[HID];
#pragma unroll
    for (int j = 0; j < HID; ++j) h[j] = b1[j];
#pragma unroll 4
    for (int i = 0; i < F_IN; ++i) {
        float xi = x[i];
#pragma unroll
        for (int j = 0; j < HID; ++j) h[j] = fmaf(xi, W1[i*HID + j], h[j]);
    }
#pragma unroll
    for (int j = 0; j < HID; ++j) h[j] = selu_f(h[j]);
#pragma unroll
    for (int j = 0; j < HID; ++j) h2[j] = b2[j];
#pragma unroll 4
    for (int k = 0; k < HID; ++k) {
        float hk = h[k];
#pragma unroll
        for (int j = 0; j < HID; ++j) h2[j] = fmaf(hk, W2[k*HID + j], h2[j]);
    }
}

// K0: pack Wh [96][32][25] f32 into MFMA 16x16x32_f16 A-fragments, ee on the
// M axis (padded 25->32 as two 16-row tiles), features on K=32.
// A-frag layout: lane l holds A[m = l&15][k = (l>>4)*8 + j], j=0..7, as 4 u32
// f16-pairs. wA[((hg*2 + t)*64 + lane)*4 + q] = pair (k = 8*(l>>4)+2q, +1)
// for ee = (l&15) + 16t (zero if ee >= 25).  Also bhp[hg][32] = padded bias.
__global__ __launch_bounds__(256) void k0_pack(const float* __restrict__ Wh,
                                               const float* __restrict__ bh,
                                               uint32_t* __restrict__ wA,
                                               float* __restrict__ bhp) {
    int t = blockIdx.x * 256 + threadIdx.x;
    if (t < N_HG * 2 * 64 * 4) {
        int q    = t & 3;
        int lane = (t >> 2) & 63;
        int tl   = (t >> 8) & 1;
        int hg   = t >> 9;
        int ee   = (lane & 15) + 16 * tl;
        int g    = lane >> 4;
        int f0   = g * 8 + q * 2;
        float a = 0.f, b = 0.f;
        if (ee < E_LEN) {
            a = Wh[hg * (HID * E_LEN) + f0 * E_LEN + ee];
            b = Wh[hg * (HID * E_LEN) + (f0 + 1) * E_LEN + ee];
        }
        half2_t p; p[0] = (_Float16)a; p[1] = (_Float16)b;
        wA[t] = __builtin_bit_cast(uint32_t, p);
    } else {
        int id = t - N_HG * 2 * 64 * 4;
        if (id < N_HG * HID) {
            int hg = id >> 5, ee = id & 31;
            bhp[id] = (ee < E_LEN) ? bh[hg * E_LEN + ee] : 0.f;
        }
    }
}

// K1: compute h2, store it, per-block (sum, sumsq) partials. 128 thr/blk
// (2 waves) x 256 blocks -> all 256 CUs covered.
__global__ __launch_bounds__(128) void k1_stats(const float* __restrict__ inp,
                                               const float* __restrict__ W1,
                                               const float* __restrict__ b1,
                                               const float* __restrict__ W2,
                                               const float* __restrict__ b2,
                                               float* __restrict__ h2out,
                                               float* __restrict__ p1,
                                               float* __restrict__ p2) {
    int tid  = threadIdx.x;
    int row  = blockIdx.x * 128 + tid;
    int lane = tid & 63;
    int wv   = tid >> 6;

    float h2[HID];
    compute_h2(inp + (size_t)row * F_IN, W1, b1, W2, b2, h2);

    float4* dst = (float4*)(h2out + (size_t)row * HID);
#pragma unroll
    for (int k = 0; k < HID / 4; ++k)
        dst[k] = make_float4(h2[4*k], h2[4*k+1], h2[4*k+2], h2[4*k+3]);

    __shared__ float s1[2][HID];
    __shared__ float s2[2][HID];
#pragma unroll
    for (int j = 0; j < HID; ++j) {
        float a = h2[j];
        float b = h2[j] * h2[j];
#pragma unroll
        for (int off = 32; off > 0; off >>= 1) {
            a += __shfl_xor(a, off, 64);
            b += __shfl_xor(b, off, 64);
        }
        if (lane == 0) { s1[wv][j] = a; s2[wv][j] = b; }
    }
    __syncthreads();
    if (tid < HID) {
        p1[blockIdx.x * HID + tid] = s1[0][tid] + s1[1][tid];
        p2[blockIdx.x * HID + tid] = s2[0][tid] + s2[1][tid];
    }
}

// K2: fold NBLK1 partials -> scale/shift per feature.
__global__ __launch_bounds__(256) void k2_fold(const float* __restrict__ p1,
                                               const float* __restrict__ p2,
                                               const float* __restrict__ gamma,
                                               const float* __restrict__ beta,
                                               float* __restrict__ ss) {
    __shared__ float l1[8][HID];
    __shared__ float l2[8][HID];
    int f = threadIdx.x & 31;
    int c = threadIdx.x >> 5;
    float a = 0.f, b = 0.f;
    for (int i = c; i < NBLK1; i += 8) {
        a += p1[i * HID + f];
        b += p2[i * HID + f];
    }
    l1[c][f] = a; l2[c][f] = b;
    __syncthreads();
    if (threadIdx.x < HID) {
        float A = 0.f, Bv = 0.f;
#pragma unroll
        for (int i = 0; i < 8; ++i) { A += l1[i][f]; Bv += l2[i][f]; }
        float mu  = A * (1.0f / (float)BATCH);
        float var = Bv * (1.0f / (float)BATCH) - mu * mu;
        float sc  = gamma[f] * rsqrtf(var + BN_EPS);
        ss[f]        = sc;
        ss[HID + f]  = beta[f] - mu * sc;
    }
}

// K4 v4: weights-stationary MFMA heads; 16 rows x 24 groups per block.
//  - 256 thr (4 waves); each wave owns 6 fixed groups; A-fragments loaded
//    once (48 VGPRs) -> zero weight traffic in the loop.
//  - e-operand built per-lane in registers (no LDS staging, no barrier).
//  - epilogue stages normalized values into a padded tile: group slots of
//    28 f32 (25 data + 3 pad) so stage writes are aligned ds_write_b128;
//    row stride 676 f32 (== 4 mod 32 -> b128 windows uniformly spread over
//    banks, stride-1-equivalent, conflict-free).
//  - flush un-pads via src = w + 3*(w/25) b32 gathers and stores float4:
//    2400 B contiguous per row at the output, dwordx4 global stores.
//  - LDS 43264 B -> 3 blocks/CU; block i+1 computes while block i drains.
#define K4_GPB 24            // groups per block
#define K4_GS  28            // padded group slot (f32)
#define K4_STR 676           // tile row stride (f32) = 24*28 + 4

__global__ __launch_bounds__(256, 3) void k4_heads(const float* __restrict__ h2buf,
                                                   const float* __restrict__ ss,
                                                   const uint32_t* __restrict__ wA,
                                                   const float* __restrict__ bhp,
                                                   float* __restrict__ out) {
    __shared__ float tile[16 * K4_STR];     // 43264 B

    int tid  = threadIdx.x;
    int lane = tid & 63;
    int wave = __builtin_amdgcn_readfirstlane(tid >> 6);  // 0..3
    int q    = blockIdx.x & 3;              // quarter of the 96 groups
    int r0   = (blockIdx.x >> 2) * 16;
    int grp  = lane >> 4;                   // 0..3
    int col  = lane & 15;                   // batch row within tile

    // Stationary weight A-fragments: 6 groups x 2 ee-tiles x 16 B
    uint4 aw[6][2];
#pragma unroll
    for (int c = 0; c < 6; ++c) {
        int hg = q * K4_GPB + wave * 6 + c;
#pragma unroll
        for (int t = 0; t < 2; ++t)
            aw[c][t] = *(const uint4*)(wA + ((hg * 2 + t) * 64 + lane) * 4);
    }

    // B-fragment in registers: lane needs e[row=col][k = grp*8 .. grp*8+7].
    f16x8 Bf;
    {
        const float* hrow = h2buf + (size_t)(r0 + col) * HID + grp * 8;
        float4 h0  = *(const float4*)hrow;
        float4 h1  = *(const float4*)(hrow + 4);
        float4 sc0 = *(const float4*)(ss + grp * 8);
        float4 sc1 = *(const float4*)(ss + grp * 8 + 4);
        float4 sh0 = *(const float4*)(ss + HID + grp * 8);
        float4 sh1 = *(const float4*)(ss + HID + grp * 8 + 4);
        float e0 = selu_f(fmaf(h0.x, sc0.x, sh0.x));
        float e1 = selu_f(fmaf(h0.y, sc0.y, sh0.y));
        float e2 = selu_f(fmaf(h0.z, sc0.z, sh0.z));
        float e3 = selu_f(fmaf(h0.w, sc0.w, sh0.w));
        float e4 = selu_f(fmaf(h1.x, sc1.x, sh1.x));
        float e5 = selu_f(fmaf(h1.y, sc1.y, sh1.y));
        float e6 = selu_f(fmaf(h1.z, sc1.z, sh1.z));
        float e7 = selu_f(fmaf(h1.w, sc1.w, sh1.w));
        f16x8 b;
        b[0] = (_Float16)e0; b[1] = (_Float16)e1; b[2] = (_Float16)e2; b[3] = (_Float16)e3;
        b[4] = (_Float16)e4; b[5] = (_Float16)e5; b[6] = (_Float16)e6; b[7] = (_Float16)e7;
        Bf = b;
    }

#pragma unroll
    for (int c = 0; c < 6; ++c) {
        int hg = q * K4_GPB + wave * 6 + c;
        int gl = wave * 6 + c;              // local group 0..23
        f32x4 zero = {0.f, 0.f, 0.f, 0.f};
        // D[m=ee][n=batch col]; this lane: n = col, ee = grp*4 + r (+16 tile1)
        f32x4 d0 = __builtin_amdgcn_mfma_f32_16x16x32_f16(
                       __builtin_bit_cast(f16x8, aw[c][0]), Bf, zero, 0, 0, 0);
        f32x4 d1 = __builtin_amdgcn_mfma_f32_16x16x32_f16(
                       __builtin_bit_cast(f16x8, aw[c][1]), Bf, zero, 0, 0, 0);
        float4 b0 = *(const float4*)(bhp + hg * HID + grp * 4);
        float4 b1 = *(const float4*)(bhp + hg * HID + 16 + grp * 4);

        float v0[4], v1[4];
        float l1 = 0.f;
        {
            float bb[4] = {b0.x, b0.y, b0.z, b0.w};
#pragma unroll
            for (int r = 0; r < 4; ++r) {
                float x = selu_f(d0[r] + bb[r]);    // ee = grp*4 + r (< 16)
                v0[r] = x; l1 += fabsf(x);
            }
        }
        {
            float bb[4] = {b1.x, b1.y, b1.z, b1.w};
#pragma unroll
            for (int r = 0; r < 4; ++r) {
                int ee1 = 16 + grp * 4 + r;
                float x = (ee1 < E_LEN) ? selu_f(d1[r] + bb[r]) : 0.f;
                v1[r] = x; l1 += fabsf(x);
            }
        }
        // sum |d| over ee for this batch row: lanes {col, col+16, col+32, col+48}
        l1 += __shfl_xor(l1, 16, 64);
        l1 += __shfl_xor(l1, 32, 64);
        float inv = 1.0f / fmaxf(l1, 1e-12f);

        float* tb = &tile[col * K4_STR + gl * K4_GS];
        *(float4*)(tb + grp * 4) =
            make_float4(v0[0] * inv, v0[1] * inv, v0[2] * inv, v0[3] * inv);
        if (grp < 3)                        // ee 16..27 (incl. zero pad 25..27)
            *(float4*)(tb + 16 + grp * 4) =
                make_float4(v1[0] * inv, v1[1] * inv, v1[2] * inv, v1[3] * inv);
    }
    asm volatile("s_waitcnt lgkmcnt(0)" ::: "memory");
    __builtin_amdgcn_s_barrier();

    // Flush: 16 rows x 600 f32 (un-pad: src = w + 3*(w/25)), float4 stores,
    // 2400 B contiguous per output row.
    float* ob = out + (size_t)r0 * (N_HG * E_LEN) + q * (K4_GPB * E_LEN);
    for (int i4 = tid; i4 < 16 * 150; i4 += 256) {
        int rr = i4 / 150;
        unsigned w = (unsigned)(i4 - rr * 150) * 4u;
        const float* trow = &tile[rr * K4_STR];
        float4 v;
        v.x = trow[w     + 3u * ((w     ) / 25u)];
        v.y = trow[w + 1u + 3u * ((w + 1u) / 25u)];
        v.z = trow[w + 2u + 3u * ((w + 2u) / 25u)];
        v.w = trow[w + 3u + 3u * ((w + 3u) / 25u)];
        *(float4*)(ob + (size_t)rr * (N_HG * E_LEN) + w) = v;
    }
}

extern "C" void kernel_launch(void* const* d_in, const int* in_sizes, int n_in,
                              void* d_out, int out_size, void* d_ws, size_t ws_size,
                              hipStream_t stream) {
    const float* inp   = (const float*)d_in[0];
    const float* W1    = (const float*)d_in[1];
    const float* b1    = (const float*)d_in[2];
    const float* W2    = (const float*)d_in[3];
    const float* b2    = (const float*)d_in[4];
    const float* gamma = (const float*)d_in[5];
    const float* beta  = (const float*)d_in[6];
    const float* Wh    = (const float*)d_in[7];
    const float* bh    = (const float*)d_in[8];
    float* out = (float*)d_out;

    char* ws = (char*)d_ws;
    uint32_t* wAb = (uint32_t*)(ws + WS_WA);
    float*    bhp = (float*)(ws + WS_BH);
    float*    p1  = (float*)(ws + WS_P1);
    float*    p2  = (float*)(ws + WS_P2);
    float*    ssb = (float*)(ws + WS_SS);
    float*    h2b = (float*)(ws + WS_H2);

    hipLaunchKernelGGL(k0_pack,  dim3(204),   dim3(256), 0, stream, Wh, bh, wAb, bhp);
    hipLaunchKernelGGL(k1_stats, dim3(NBLK1), dim3(128), 0, stream, inp, W1, b1, W2, b2, h2b, p1, p2);
    hipLaunchKernelGGL(k2_fold,  dim3(1),     dim3(256), 0, stream, p1, p2, gamma, beta, ssb);
    hipLaunchKernelGGL(k4_heads, dim3((BATCH / 16) * 4), dim3(256), 0, stream, h2b, ssb, wAb, bhp, out);
}

// Round 5
// 395.506 us; speedup vs baseline: 1.4976x; 1.0659x over previous
//
#include <hip/hip_runtime.h>
#include <stdint.h>

// Problem constants
#define BATCH   32768
#define F_IN    64
#define HID     32
#define E_LEN   25
#define N_HG    96           // H*G
#define BN_EPS  1e-5f

#define PACKB   193          // pack blocks in fused k01 (192 wA + 1 bias)
#define NBLK1   512          // stats blocks (256 thr, 64 rows each)

// ws layout (bytes)
#define WS_WA   0            // heads A-frags: 96*2*64*4 u32 = 196608
#define WS_BH   196608       // padded bias 96*32 f32 = 12288 (region 16384)
#define WS_P1   212992       // 512*32 f32 partial sums   (65536)
#define WS_P2   278528       // 512*32 f32 partial sumsq  (65536)
#define WS_SS   344064       // 64 f32: scale[32], shift[32] (256)
#define WS_H2   344320       // 32768*32 f32 h2 rows (4 MB)

typedef _Float16 half2_t __attribute__((ext_vector_type(2)));
typedef _Float16 f16x4   __attribute__((ext_vector_type(4)));
typedef _Float16 f16x8   __attribute__((ext_vector_type(8)));
typedef float    f32x4   __attribute__((ext_vector_type(4)));

__device__ __forceinline__ float selu_f(float x) {
    const float lam = 1.0507009873554805f;
    const float la  = 1.7580993408473766f;   // lam * alpha
    return x > 0.f ? lam * x : la * (__expf(x) - 1.f);
}

__device__ __forceinline__ uint32_t pk2(float a, float b) {
    half2_t p; p[0] = (_Float16)a; p[1] = (_Float16)b;
    return __builtin_bit_cast(uint32_t, p);
}

// K01: fused pack + MFMA feature-extractor stats.
//  blocks [0,192):  pack Wh -> heads MFMA A-frags (consumed by k4 ONLY ->
//                   no intra-launch dependency)
//  block  192:      padded heads bias (consumed by k4 ONLY)
//  blocks [193,705): feature extractor, 64 rows/block (16/wave):
//    W1/W2 compensated f16 fragments are built IN-REGISTER from global by
//    each block itself (48 cached scalar loads/thread; W1+W2 = 12 KB,
//    L1-resident) -- NO cross-block producer/consumer within this launch
//    (round-4 bug: stats blocks raced ahead of the pack blocks).
//    layer1: h = selu(X@W1+b1), 2x 16x16x32_f16 m-tiles, K=64 in 2 steps,
//            compensated (Xhi*Whi + Xlo*Whi + Xhi*Wlo) -> error ~1e-6.
//    layer2: h2 = h@W2+b2 via 16x16x16f16; its B-frag layout
//            (k = 4*(lane>>4)+j) EQUALS layer1's D layout (m = 4*(lane>>4)+r)
//            -> no LDS, no shuffles between layers.
//    then h2 store (coalesced float4) + per-block (sum,sumsq) partials.
__global__ __launch_bounds__(256) void k01_fused(const float* __restrict__ inp,
                                                 const float* __restrict__ W1,
                                                 const float* __restrict__ b1,
                                                 const float* __restrict__ W2,
                                                 const float* __restrict__ b2,
                                                 const float* __restrict__ Wh,
                                                 const float* __restrict__ bh,
                                                 uint32_t* __restrict__ wA,
                                                 float* __restrict__ bhp,
                                                 float* __restrict__ h2out,
                                                 float* __restrict__ p1,
                                                 float* __restrict__ p2) {
    int tid = threadIdx.x;
    int bid = blockIdx.x;

    if (bid < 192) {
        // ---- heads A-frag pack (verified) ----
        int t    = bid * 256 + tid;
        int q    = t & 3;
        int lane = (t >> 2) & 63;
        int tl   = (t >> 8) & 1;
        int hg   = t >> 9;
        int ee   = (lane & 15) + 16 * tl;
        int g    = lane >> 4;
        int f0   = g * 8 + q * 2;
        float a = 0.f, b = 0.f;
        if (ee < E_LEN) {
            a = Wh[hg * (HID * E_LEN) + f0 * E_LEN + ee];
            b = Wh[hg * (HID * E_LEN) + (f0 + 1) * E_LEN + ee];
        }
        wA[t] = pk2(a, b);
        return;
    }
    if (bid < PACKB) {
        // ---- padded heads bias ----
        for (int i = tid; i < N_HG * HID; i += 256) {
            int hg = i >> 5, ee = i & 31;
            bhp[i] = (ee < E_LEN) ? bh[hg * E_LEN + ee] : 0.f;
        }
        return;
    }

    // ---- stats path (self-contained) ----
    __shared__ float sP1[4][HID];
    __shared__ float sP2[4][HID];

    int sb   = bid - PACKB;
    int lane = tid & 63;
    int wv   = tid >> 6;
    int c    = lane & 15;                 // batch row within 16-tile / m-col
    int q    = lane >> 4;                 // k/m lane-group
    int r0   = (sb * 4 + wv) * 16;

    // In-register compensated W1 A-frags: element j of (t,s) =
    // W1[32s + 8q + j][16t + c]  (A[m][k] = W1[k][m], m = l&15, k = 8*(l>>4)+j)
    f16x8 W1hf[2][2], W1lf[2][2];
#pragma unroll
    for (int t = 0; t < 2; ++t)
#pragma unroll
        for (int s = 0; s < 2; ++s) {
            f16x8 hi, lo;
#pragma unroll
            for (int j = 0; j < 8; ++j) {
                float v = W1[(32 * s + 8 * q + j) * HID + 16 * t + c];
                _Float16 hv = (_Float16)v;
                hi[j] = hv;
                lo[j] = (_Float16)(v - (float)hv);
            }
            W1hf[t][s] = hi; W1lf[t][s] = lo;
        }
    // W2 A-frags (x16 shape): element j of (t,s) = W2[16s + 4q + j][16t + c]
    f16x4 W2hf[2][2], W2lf[2][2];
#pragma unroll
    for (int t = 0; t < 2; ++t)
#pragma unroll
        for (int s = 0; s < 2; ++s) {
            f16x4 hi, lo;
#pragma unroll
            for (int j = 0; j < 4; ++j) {
                float v = W2[(16 * s + 4 * q + j) * HID + 16 * t + c];
                _Float16 hv = (_Float16)v;
                hi[j] = hv;
                lo[j] = (_Float16)(v - (float)hv);
            }
            W2hf[t][s] = hi; W2lf[t][s] = lo;
        }

    // X row chunk -> compensated f16 B-frags for 16x16x32 (k = 8q..8q+7 +32s)
    f16x8 Bh[2], Bl[2];
    {
        const float* xr = inp + (size_t)(r0 + c) * F_IN;
#pragma unroll
        for (int s = 0; s < 2; ++s) {
            float4 a = *(const float4*)(xr + 32 * s + 8 * q);
            float4 b = *(const float4*)(xr + 32 * s + 8 * q + 4);
            float e[8] = {a.x, a.y, a.z, a.w, b.x, b.y, b.z, b.w};
            f16x8 hi, lo;
#pragma unroll
            for (int j = 0; j < 8; ++j) {
                _Float16 h = (_Float16)e[j];
                hi[j] = h;
                lo[j] = (_Float16)(e[j] - (float)h);
            }
            Bh[s] = hi; Bl[s] = lo;
        }
    }

    // Layer1: 2 m-tiles x (2 ksteps x 3 compensated products)
    f32x4 D[2];
#pragma unroll
    for (int t = 0; t < 2; ++t) {
        f32x4 acc = {0.f, 0.f, 0.f, 0.f};
#pragma unroll
        for (int s = 0; s < 2; ++s) {
            acc = __builtin_amdgcn_mfma_f32_16x16x32_f16(W1hf[t][s], Bh[s], acc, 0, 0, 0);
            acc = __builtin_amdgcn_mfma_f32_16x16x32_f16(W1lf[t][s], Bh[s], acc, 0, 0, 0);
            acc = __builtin_amdgcn_mfma_f32_16x16x32_f16(W1hf[t][s], Bl[s], acc, 0, 0, 0);
        }
        D[t] = acc;
    }

    // bias + selu; split into compensated f16 B-frags for layer2 (x16 shape).
    // Layer1 D (m = 4q+r, tile t) == layer2 B kstep t (k = 4q+j) layout.
    f16x4 Hh[2], Hl[2];
#pragma unroll
    for (int t = 0; t < 2; ++t) {
        float4 bv = *(const float4*)(b1 + 16 * t + 4 * q);
        float bb[4] = {bv.x, bv.y, bv.z, bv.w};
        f16x4 hi, lo;
#pragma unroll
        for (int r = 0; r < 4; ++r) {
            float h = selu_f(D[t][r] + bb[r]);
            _Float16 hh = (_Float16)h;
            hi[r] = hh;
            lo[r] = (_Float16)(h - (float)hh);
        }
        Hh[t] = hi; Hl[t] = lo;
    }

    // Layer2: 2 m-tiles x (2 ksteps x 3 compensated products), 16x16x16f16
    float h2v[2][4];
#pragma unroll
    for (int t = 0; t < 2; ++t) {
        f32x4 acc = {0.f, 0.f, 0.f, 0.f};
#pragma unroll
        for (int s = 0; s < 2; ++s) {
            acc = __builtin_amdgcn_mfma_f32_16x16x16f16(W2hf[t][s], Hh[s], acc, 0, 0, 0);
            acc = __builtin_amdgcn_mfma_f32_16x16x16f16(W2lf[t][s], Hh[s], acc, 0, 0, 0);
            acc = __builtin_amdgcn_mfma_f32_16x16x16f16(W2hf[t][s], Hl[s], acc, 0, 0, 0);
        }
        float4 bv = *(const float4*)(b2 + 16 * t + 4 * q);
        float bb[4] = {bv.x, bv.y, bv.z, bv.w};
#pragma unroll
        for (int r = 0; r < 4; ++r) h2v[t][r] = acc[r] + bb[r];
    }

    // h2 store: per m-tile a float4 at h2out[row][16t + 4q]
#pragma unroll
    for (int t = 0; t < 2; ++t)
        *(float4*)(h2out + (size_t)(r0 + c) * HID + 16 * t + 4 * q) =
            make_float4(h2v[t][0], h2v[t][1], h2v[t][2], h2v[t][3]);

    // stats: reduce over the 16 batch rows (c) within each 16-lane group
#pragma unroll
    for (int t = 0; t < 2; ++t) {
#pragma unroll
        for (int r = 0; r < 4; ++r) {
            float a = h2v[t][r];
            float b = a * a;
#pragma unroll
            for (int off = 1; off < 16; off <<= 1) {
                a += __shfl_xor(a, off, 64);
                b += __shfl_xor(b, off, 64);
            }
            if (c == 0) {
                int j2 = 16 * t + 4 * q + r;
                sP1[wv][j2] = a;
                sP2[wv][j2] = b;
            }
        }
    }
    __syncthreads();
    if (tid < HID) {
        float A = 0.f, B = 0.f;
#pragma unroll
        for (int w = 0; w < 4; ++w) { A += sP1[w][tid]; B += sP2[w][tid]; }
        p1[sb * HID + tid] = A;
        p2[sb * HID + tid] = B;
    }
}

// K2: fold NBLK1 partials -> scale/shift per feature.
__global__ __launch_bounds__(256) void k2_fold(const float* __restrict__ p1,
                                               const float* __restrict__ p2,
                                               const float* __restrict__ gamma,
                                               const float* __restrict__ beta,
                                               float* __restrict__ ss) {
    __shared__ float l1[8][HID];
    __shared__ float l2[8][HID];
    int f = threadIdx.x & 31;
    int c = threadIdx.x >> 5;
    float a = 0.f, b = 0.f;
    for (int i = c; i < NBLK1; i += 8) {
        a += p1[i * HID + f];
        b += p2[i * HID + f];
    }
    l1[c][f] = a; l2[c][f] = b;
    __syncthreads();
    if (threadIdx.x < HID) {
        float A = 0.f, Bv = 0.f;
#pragma unroll
        for (int i = 0; i < 8; ++i) { A += l1[i][f]; Bv += l2[i][f]; }
        float mu  = A * (1.0f / (float)BATCH);
        float var = Bv * (1.0f / (float)BATCH) - mu * mu;
        float sc  = gamma[f] * rsqrtf(var + BN_EPS);
        ss[f]        = sc;
        ss[HID + f]  = beta[f] - mu * sc;
    }
}

// K4 (unchanged, verified): weights-stationary MFMA heads; 16 rows x 24
// groups per block; padded-slot LDS stage (conflict-free ds_write_b128);
// un-pad flush with 2400 B contiguous runs, dwordx4 stores.
#define K4_GPB 24            // groups per block
#define K4_GS  28            // padded group slot (f32)
#define K4_STR 676           // tile row stride (f32) = 24*28 + 4

__global__ __launch_bounds__(256, 3) void k4_heads(const float* __restrict__ h2buf,
                                                   const float* __restrict__ ss,
                                                   const uint32_t* __restrict__ wA,
                                                   const float* __restrict__ bhp,
                                                   float* __restrict__ out) {
    __shared__ float tile[16 * K4_STR];     // 43264 B

    int tid  = threadIdx.x;
    int lane = tid & 63;
    int wave = __builtin_amdgcn_readfirstlane(tid >> 6);  // 0..3
    int q    = blockIdx.x & 3;              // quarter of the 96 groups
    int r0   = (blockIdx.x >> 2) * 16;
    int grp  = lane >> 4;                   // 0..3
    int col  = lane & 15;                   // batch row within tile

    uint4 aw[6][2];
#pragma unroll
    for (int c = 0; c < 6; ++c) {
        int hg = q * K4_GPB + wave * 6 + c;
#pragma unroll
        for (int t = 0; t < 2; ++t)
            aw[c][t] = *(const uint4*)(wA + ((hg * 2 + t) * 64 + lane) * 4);
    }

    f16x8 Bf;
    {
        const float* hrow = h2buf + (size_t)(r0 + col) * HID + grp * 8;
        float4 h0  = *(const float4*)hrow;
        float4 h1  = *(const float4*)(hrow + 4);
        float4 sc0 = *(const float4*)(ss + grp * 8);
        float4 sc1 = *(const float4*)(ss + grp * 8 + 4);
        float4 sh0 = *(const float4*)(ss + HID + grp * 8);
        float4 sh1 = *(const float4*)(ss + HID + grp * 8 + 4);
        float e0 = selu_f(fmaf(h0.x, sc0.x, sh0.x));
        float e1 = selu_f(fmaf(h0.y, sc0.y, sh0.y));
        float e2 = selu_f(fmaf(h0.z, sc0.z, sh0.z));
        float e3 = selu_f(fmaf(h0.w, sc0.w, sh0.w));
        float e4 = selu_f(fmaf(h1.x, sc1.x, sh1.x));
        float e5 = selu_f(fmaf(h1.y, sc1.y, sh1.y));
        float e6 = selu_f(fmaf(h1.z, sc1.z, sh1.z));
        float e7 = selu_f(fmaf(h1.w, sc1.w, sh1.w));
        f16x8 b;
        b[0] = (_Float16)e0; b[1] = (_Float16)e1; b[2] = (_Float16)e2; b[3] = (_Float16)e3;
        b[4] = (_Float16)e4; b[5] = (_Float16)e5; b[6] = (_Float16)e6; b[7] = (_Float16)e7;
        Bf = b;
    }

#pragma unroll
    for (int c = 0; c < 6; ++c) {
        int hg = q * K4_GPB + wave * 6 + c;
        int gl = wave * 6 + c;              // local group 0..23
        f32x4 zero = {0.f, 0.f, 0.f, 0.f};
        f32x4 d0 = __builtin_amdgcn_mfma_f32_16x16x32_f16(
                       __builtin_bit_cast(f16x8, aw[c][0]), Bf, zero, 0, 0, 0);
        f32x4 d1 = __builtin_amdgcn_mfma_f32_16x16x32_f16(
                       __builtin_bit_cast(f16x8, aw[c][1]), Bf, zero, 0, 0, 0);
        float4 b0 = *(const float4*)(bhp + hg * HID + grp * 4);
        float4 b1 = *(const float4*)(bhp + hg * HID + 16 + grp * 4);

        float v0[4], v1[4];
        float l1 = 0.f;
        {
            float bb[4] = {b0.x, b0.y, b0.z, b0.w};
#pragma unroll
            for (int r = 0; r < 4; ++r) {
                float x = selu_f(d0[r] + bb[r]);
                v0[r] = x; l1 += fabsf(x);
            }
        }
        {
            float bb[4] = {b1.x, b1.y, b1.z, b1.w};
#pragma unroll
            for (int r = 0; r < 4; ++r) {
                int ee1 = 16 + grp * 4 + r;
                float x = (ee1 < E_LEN) ? selu_f(d1[r] + bb[r]) : 0.f;
                v1[r] = x; l1 += fabsf(x);
            }
        }
        l1 += __shfl_xor(l1, 16, 64);
        l1 += __shfl_xor(l1, 32, 64);
        float inv = 1.0f / fmaxf(l1, 1e-12f);

        float* tb = &tile[col * K4_STR + gl * K4_GS];
        *(float4*)(tb + grp * 4) =
            make_float4(v0[0] * inv, v0[1] * inv, v0[2] * inv, v0[3] * inv);
        if (grp < 3)
            *(float4*)(tb + 16 + grp * 4) =
                make_float4(v1[0] * inv, v1[1] * inv, v1[2] * inv, v1[3] * inv);
    }
    asm volatile("s_waitcnt lgkmcnt(0)" ::: "memory");
    __builtin_amdgcn_s_barrier();

    float* ob = out + (size_t)r0 * (N_HG * E_LEN) + q * (K4_GPB * E_LEN);
    for (int i4 = tid; i4 < 16 * 150; i4 += 256) {
        int rr = i4 / 150;
        unsigned w = (unsigned)(i4 - rr * 150) * 4u;
        const float* trow = &tile[rr * K4_STR];
        float4 v;
        v.x = trow[w     + 3u * ((w     ) / 25u)];
        v.y = trow[w + 1u + 3u * ((w + 1u) / 25u)];
        v.z = trow[w + 2u + 3u * ((w + 2u) / 25u)];
        v.w = trow[w + 3u + 3u * ((w + 3u) / 25u)];
        *(float4*)(ob + (size_t)rr * (N_HG * E_LEN) + w) = v;
    }
}

extern "C" void kernel_launch(void* const* d_in, const int* in_sizes, int n_in,
                              void* d_out, int out_size, void* d_ws, size_t ws_size,
                              hipStream_t stream) {
    const float* inp   = (const float*)d_in[0];
    const float* W1    = (const float*)d_in[1];
    const float* b1    = (const float*)d_in[2];
    const float* W2    = (const float*)d_in[3];
    const float* b2    = (const float*)d_in[4];
    const float* gamma = (const float*)d_in[5];
    const float* beta  = (const float*)d_in[6];
    const float* Wh    = (const float*)d_in[7];
    const float* bh    = (const float*)d_in[8];
    float* out = (float*)d_out;

    char* ws = (char*)d_ws;
    uint32_t* wAb = (uint32_t*)(ws + WS_WA);
    float*    bhp = (float*)(ws + WS_BH);
    float*    p1  = (float*)(ws + WS_P1);
    float*    p2  = (float*)(ws + WS_P2);
    float*    ssb = (float*)(ws + WS_SS);
    float*    h2b = (float*)(ws + WS_H2);

    hipLaunchKernelGGL(k01_fused, dim3(PACKB + NBLK1), dim3(256), 0, stream,
                       inp, W1, b1, W2, b2, Wh, bh,
                       wAb, bhp, h2b, p1, p2);
    hipLaunchKernelGGL(k2_fold,  dim3(1),    dim3(256), 0, stream, p1, p2, gamma, beta, ssb);
    hipLaunchKernelGGL(k4_heads, dim3((BATCH / 16) * 4), dim3(256), 0, stream, h2b, ssb, wAb, bhp, out);
}